// Round 6
// baseline (536.506 us; speedup 1.0000x reference)
//
#include <hip/hip_runtime.h>
#include <hip/hip_bf16.h>

// EdgeWeightFromDistance: out[e] = relu(relu([x[src], y[dst], dist] @ W1 + b1) @ W2 + b2)
// E = 1e6, NODE_DIM = 64, HIDDEN = 128.
// R10: R9 post-mortem — swizzle: SQ_LDS_BANK_CONFLICT identical 5.18M (conflicts are
//      shfl/bpermute, not Wt reads; axis dead). Pipeline: WRITE_SIZE 3.9->33 MB = scratch
//      spill. Model (3 independent confirmations): time = beyond-L2 bytes / ~2.9 TB/s.
//      Only lever left: reduce bytes. 163 MB >> compulsory: x-rows have 10x reuse that
//      random order spreads across 8 non-shared 4-MB L2s.
//      R10 = src-bucket partition (8 buckets of ~12.5K nodes = 1.6 MB xb slice / bucket)
//      + XCD-affinity tile claiming (s_getreg XCC_ID, m09-verified) + work-stealing
//      sweep so correctness never depends on the mapping (G16). Each XCD keeps its
//      bucket's x-slice L2-resident across all ~10 uses: x misses ~78 -> ~13 MB.
//      Compute core = R6's verified 62-µs body, bit-identical per-edge math.

constexpr int NDIM  = 64;
constexpr int HID   = 128;
constexpr int KPAD  = 136;   // bf16 elems per Wt row: 128 data + w1r + b1 + 6 zeros
constexpr int NB    = 8;     // src buckets == XCDs
// meta layout (ints): [0..8) cnt, [8..17) off, [17..25) scatter cur, [25..33) tile cur
constexpr int M_CNT = 0, M_OFF = 8, M_CUR = 17, M_TC = 25, M_TOT = 33;

typedef __attribute__((ext_vector_type(8))) short  short8;
typedef __attribute__((ext_vector_type(4))) int    int4v;
typedef __attribute__((ext_vector_type(4))) float  floatx4;

__device__ __forceinline__ short f2bf(float f) {
    union { __hip_bfloat16 h; short s; } cv;
    cv.h = __float2bfloat16(f);
    return cv.s;
}

__device__ __forceinline__ int pack2(float a, float b) {
    union { __hip_bfloat162 h; int u; } cv;
    cv.h = __float22bfloat162_rn(float2{a, b});
    return cv.u;
}

__device__ __forceinline__ short8 make_afrag_f32(const float* rp) {
    const floatx4 f0 = *reinterpret_cast<const floatx4*>(rp);
    const floatx4 f1 = *reinterpret_cast<const floatx4*>(rp + 4);
    union { int4v i; short8 s8; } cv;
    cv.i.x = pack2(f0.x, f0.y);
    cv.i.y = pack2(f0.z, f0.w);
    cv.i.z = pack2(f1.x, f1.y);
    cv.i.w = pack2(f1.z, f1.w);
    return cv.s8;
}

// ---- streaming fp32 -> bf16 convert of x and y into workspace ----
__global__ __launch_bounds__(256) void cvt_kernel(
    const float* __restrict__ xin, const float* __restrict__ yin,
    short* __restrict__ xb, short* __restrict__ yb, int nfl)
{
    const int stride = gridDim.x * blockDim.x;
    const int n8 = nfl >> 3;
    for (int i = blockIdx.x * blockDim.x + threadIdx.x; i < n8; i += stride) {
        {
            const floatx4 f0 = *reinterpret_cast<const floatx4*>(xin + i * 8);
            const floatx4 f1 = *reinterpret_cast<const floatx4*>(xin + i * 8 + 4);
            union { int4v v; short8 s; } c;
            c.v.x = pack2(f0.x, f0.y); c.v.y = pack2(f0.z, f0.w);
            c.v.z = pack2(f1.x, f1.y); c.v.w = pack2(f1.z, f1.w);
            *reinterpret_cast<short8*>(xb + i * 8) = c.s;
        }
        {
            const floatx4 f0 = *reinterpret_cast<const floatx4*>(yin + i * 8);
            const floatx4 f1 = *reinterpret_cast<const floatx4*>(yin + i * 8 + 4);
            union { int4v v; short8 s; } c;
            c.v.x = pack2(f0.x, f0.y); c.v.y = pack2(f0.z, f0.w);
            c.v.z = pack2(f1.x, f1.y); c.v.w = pack2(f1.z, f1.w);
            *reinterpret_cast<short8*>(yb + i * 8) = c.s;
        }
    }
}

// ---- bucket partition kernels ----
__global__ __launch_bounds__(64) void zero_meta_kernel(int* __restrict__ meta) {
    if (threadIdx.x < M_TOT) meta[threadIdx.x] = 0;
}

__global__ __launch_bounds__(256) void hist_kernel(
    const int* __restrict__ ei, int E, float inv, int* __restrict__ meta)
{
    __shared__ int h[NB];
    const int tid = threadIdx.x;
    if (tid < NB) h[tid] = 0;
    __syncthreads();
    const int stride = gridDim.x * blockDim.x;
    for (int e = blockIdx.x * blockDim.x + tid; e < E; e += stride) {
        const int s = ei[e];
        int b = (int)((float)s * inv);
        if (b > NB - 1) b = NB - 1;
        atomicAdd(&h[b], 1);
    }
    __syncthreads();
    if (tid < NB && h[tid] > 0) atomicAdd(&meta[M_CNT + tid], h[tid]);
}

__global__ __launch_bounds__(64) void scan_kernel(int* __restrict__ meta) {
    if (threadIdx.x == 0) {
        int acc = 0;
        for (int b = 0; b < NB; ++b) {
            meta[M_OFF + b] = acc;
            meta[M_CUR + b] = acc;
            acc += meta[M_CNT + b];
        }
        meta[M_OFF + NB] = acc;
    }
}

__global__ __launch_bounds__(256) void scatter_kernel(
    const int* __restrict__ ei, int E, float inv, int* __restrict__ meta,
    int* __restrict__ sSrc, int* __restrict__ sDst, int* __restrict__ sId)
{
    __shared__ int h[NB], base8[NB], c2[NB];
    const int tid = threadIdx.x;
    const int* srcp = ei;
    const int* dstp = ei + E;
    int* cur = meta + M_CUR;
    const int C  = (E + gridDim.x - 1) / gridDim.x;
    const int lo = blockIdx.x * C;
    const int hi = (lo + C < E) ? (lo + C) : E;
    for (int s0 = lo; s0 < hi; s0 += 256) {
        const int e = s0 + tid;
        const bool valid = e < hi;
        int s = 0, d = 0, b = 0;
        if (tid < NB) { h[tid] = 0; c2[tid] = 0; }
        __syncthreads();
        if (valid) {
            s = srcp[e]; d = dstp[e];
            b = (int)((float)s * inv);
            if (b > NB - 1) b = NB - 1;
            atomicAdd(&h[b], 1);
        }
        __syncthreads();
        if (tid < NB && h[tid] > 0) base8[tid] = atomicAdd(&cur[tid], h[tid]);
        __syncthreads();
        if (valid) {
            const int r   = atomicAdd(&c2[b], 1);
            const int pos = base8[b] + r;
            sSrc[pos] = s; sDst[pos] = d; sId[pos] = e;
        }
        __syncthreads();
    }
}

// ================= fallback (R6, verified 62 µs): unsorted edges =================
template <bool BF16GATHER>
__global__ __launch_bounds__(256, 4) void edge_mlp_kernel(
    const float* __restrict__ x, const float* __restrict__ y,
    const short* __restrict__ xb, const short* __restrict__ yb,
    const int*  __restrict__ ei, const float* __restrict__ px,
    const float* __restrict__ py, const float* __restrict__ W1,
    const float* __restrict__ b1, const float* __restrict__ W2,
    const float* __restrict__ b2, float* __restrict__ out, int E)
{
    __shared__ __align__(16) short Wt[HID * KPAD];
    const int tid = threadIdx.x;
    for (int base = 0; base < HID * HID; base += 256 * 8) {
        float f[8];
#pragma unroll
        for (int u = 0; u < 8; ++u) f[u] = W1[base + u * 256 + tid];
#pragma unroll
        for (int u = 0; u < 8; ++u) {
            int i = base + u * 256 + tid;
            Wt[(i & 127) * KPAD + (i >> 7)] = f2bf(f[u]);
        }
    }
    if (tid < HID) {
        const int n = tid;
        Wt[n * KPAD + 128] = f2bf(W1[128 * HID + n]);
        Wt[n * KPAD + 129] = f2bf(b1[n]);
#pragma unroll
        for (int j = 130; j < 136; ++j) Wt[n * KPAD + j] = 0;
    }
    __syncthreads();

    const int lane = tid & 63;
    const int wave = tid >> 6;
    const int quad = lane >> 4;
    const int lm   = lane & 15;

    float w2v[8];
#pragma unroll
    for (int t = 0; t < 8; ++t) w2v[t] = W2[t * 16 + lm];
    const float b2s = b2[0];

    const int* __restrict__ srcp = ei;
    const int* __restrict__ dstp = ei + E;
    const int sel5 = (quad == 0) ? 128 : 0;

    const int ntiles = (E + 127) / 128;
    for (int tile = blockIdx.x; tile < ntiles; tile += gridDim.x) {
        const int mb = tile * 128 + wave * 32;
        int m0 = mb + lm;       if (m0 >= E) m0 = E - 1;
        int m1 = mb + 16 + lm;  if (m1 >= E) m1 = E - 1;
        const int src0 = srcp[m0], dst0 = dstp[m0];
        const int src1 = srcp[m1], dst1 = dstp[m1];

        float dd = 0.f;
        if (lane < 32) {
            const int ps = (lane < 16) ? src0 : src1;
            const int pd = (lane < 16) ? dst0 : dst1;
            const float ax = px[ps * 3 + 0] - py[pd * 3 + 0];
            const float ay = px[ps * 3 + 1] - py[pd * 3 + 1];
            const float az = px[ps * 3 + 2] - py[pd * 3 + 2];
            dd = sqrtf(ax * ax + ay * ay + az * az);
        }
        const float dist0 = __shfl(dd, lm, 64);
        const float dist1 = __shfl(dd, lm + 16, 64);

        short8 fa[4], fb[4];
#pragma unroll
        for (int s = 0; s < 4; ++s) {
            const int kk = s * 32 + quad * 8;
            if (BF16GATHER) {
                const short* pa = (s < 2) ? (xb + src0 * NDIM + kk)
                                          : (yb + dst0 * NDIM + (kk - 64));
                const short* pb = (s < 2) ? (xb + src1 * NDIM + kk)
                                          : (yb + dst1 * NDIM + (kk - 64));
                fa[s] = *reinterpret_cast<const short8*>(pa);
                fb[s] = *reinterpret_cast<const short8*>(pb);
            } else {
                fa[s] = make_afrag_f32((s < 2) ? (x + src0 * NDIM + kk)
                                               : (y + dst0 * NDIM + (kk - 64)));
                fb[s] = make_afrag_f32((s < 2) ? (x + src1 * NDIM + kk)
                                               : (y + dst1 * NDIM + (kk - 64)));
            }
        }
        short8 fa4, fb4;
        {
            union { int4v i; short8 s8; } ca, cb;
            const int d0 = (quad == 0) ? pack2(dist0, 1.0f) : 0;
            const int d1 = (quad == 0) ? pack2(dist1, 1.0f) : 0;
            ca.i = int4v{d0, 0, 0, 0};
            cb.i = int4v{d1, 0, 0, 0};
            fa4 = ca.s8; fb4 = cb.s8;
        }

        float p0 = 0.f, p1 = 0.f, p2 = 0.f, p3 = 0.f;
        float q0 = 0.f, q1 = 0.f, q2 = 0.f, q3 = 0.f;
        int zoff = 0;
        asm volatile("" : "+v"(zoff));
        const short* wr  = Wt + zoff + lm * KPAD + quad * 8;
        const short* wr5 = Wt + zoff + lm * KPAD + sel5;

#pragma unroll
        for (int half = 0; half < 2; ++half) {
            if (half) __builtin_amdgcn_sched_barrier(0);
            floatx4 aA[4], aB[4];
#pragma unroll
            for (int u = 0; u < 4; ++u) {
                aA[u] = floatx4{0.f, 0.f, 0.f, 0.f};
                aB[u] = floatx4{0.f, 0.f, 0.f, 0.f};
            }
#pragma unroll
            for (int u = 0; u < 4; ++u) {
                const int t = half * 4 + u;
                const short* base = wr + t * (16 * KPAD);
                const short8 bg0 = *reinterpret_cast<const short8*>(base);
                const short8 bg1 = *reinterpret_cast<const short8*>(base + 32);
                const short8 bg2 = *reinterpret_cast<const short8*>(base + 64);
                const short8 bg3 = *reinterpret_cast<const short8*>(base + 96);
                const short8 bg4 = *reinterpret_cast<const short8*>(wr5 + t * (16 * KPAD));
                aA[u] = __builtin_amdgcn_mfma_f32_16x16x32_bf16(fa[0], bg0, aA[u], 0, 0, 0);
                aB[u] = __builtin_amdgcn_mfma_f32_16x16x32_bf16(fb[0], bg0, aB[u], 0, 0, 0);
                aA[u] = __builtin_amdgcn_mfma_f32_16x16x32_bf16(fa[1], bg1, aA[u], 0, 0, 0);
                aB[u] = __builtin_amdgcn_mfma_f32_16x16x32_bf16(fb[1], bg1, aB[u], 0, 0, 0);
                aA[u] = __builtin_amdgcn_mfma_f32_16x16x32_bf16(fa[2], bg2, aA[u], 0, 0, 0);
                aB[u] = __builtin_amdgcn_mfma_f32_16x16x32_bf16(fb[2], bg2, aB[u], 0, 0, 0);
                aA[u] = __builtin_amdgcn_mfma_f32_16x16x32_bf16(fa[3], bg3, aA[u], 0, 0, 0);
                aB[u] = __builtin_amdgcn_mfma_f32_16x16x32_bf16(fb[3], bg3, aB[u], 0, 0, 0);
                aA[u] = __builtin_amdgcn_mfma_f32_16x16x32_bf16(fa4,   bg4, aA[u], 0, 0, 0);
                aB[u] = __builtin_amdgcn_mfma_f32_16x16x32_bf16(fb4,   bg4, aB[u], 0, 0, 0);
            }
#pragma unroll
            for (int u = 0; u < 4; ++u) {
                const float w = w2v[half * 4 + u];
                p0 += fmaxf(aA[u][0], 0.f) * w;
                p1 += fmaxf(aA[u][1], 0.f) * w;
                p2 += fmaxf(aA[u][2], 0.f) * w;
                p3 += fmaxf(aA[u][3], 0.f) * w;
                q0 += fmaxf(aB[u][0], 0.f) * w;
                q1 += fmaxf(aB[u][1], 0.f) * w;
                q2 += fmaxf(aB[u][2], 0.f) * w;
                q3 += fmaxf(aB[u][3], 0.f) * w;
            }
        }

#pragma unroll
        for (int off = 1; off < 16; off <<= 1) {
            p0 += __shfl_xor(p0, off, 64);
            p1 += __shfl_xor(p1, off, 64);
            p2 += __shfl_xor(p2, off, 64);
            p3 += __shfl_xor(p3, off, 64);
            q0 += __shfl_xor(q0, off, 64);
            q1 += __shfl_xor(q1, off, 64);
            q2 += __shfl_xor(q2, off, 64);
            q3 += __shfl_xor(q3, off, 64);
        }
        if (lm < 4) {
            const float vA = (lm == 0) ? p0 : (lm == 1) ? p1 : (lm == 2) ? p2 : p3;
            const float vB = (lm == 0) ? q0 : (lm == 1) ? q1 : (lm == 2) ? q2 : q3;
            const int eA = mb + quad * 4 + lm;
            const int eB = mb + 16 + quad * 4 + lm;
            if (eA < E) out[eA] = fmaxf(vA + b2s, 0.f);
            if (eB < E) out[eB] = fmaxf(vB + b2s, 0.f);
        }
    }
}

// ================= sorted main kernel: XCD-affinity bucket claiming =================
__global__ __launch_bounds__(256, 4) void edge_mlp_sorted_kernel(
    const short* __restrict__ xb, const short* __restrict__ yb,
    const int* __restrict__ sSrc, const int* __restrict__ sDst,
    const int* __restrict__ sId,
    const float* __restrict__ px, const float* __restrict__ py,
    const float* __restrict__ W1, const float* __restrict__ b1,
    const float* __restrict__ W2, const float* __restrict__ b2,
    float* __restrict__ out, int E, int* meta)
{
    __shared__ __align__(16) short Wt[HID * KPAD];
    __shared__ int sTile;
    const int tid = threadIdx.x;

    for (int base = 0; base < HID * HID; base += 256 * 8) {
        float f[8];
#pragma unroll
        for (int u = 0; u < 8; ++u) f[u] = W1[base + u * 256 + tid];
#pragma unroll
        for (int u = 0; u < 8; ++u) {
            int i = base + u * 256 + tid;
            Wt[(i & 127) * KPAD + (i >> 7)] = f2bf(f[u]);
        }
    }
    if (tid < HID) {
        const int n = tid;
        Wt[n * KPAD + 128] = f2bf(W1[128 * HID + n]);
        Wt[n * KPAD + 129] = f2bf(b1[n]);
#pragma unroll
        for (int j = 130; j < 136; ++j) Wt[n * KPAD + j] = 0;
    }
    __syncthreads();

    const int lane = tid & 63;
    const int wave = tid >> 6;
    const int quad = lane >> 4;
    const int lm   = lane & 15;

    float w2v[8];
#pragma unroll
    for (int t = 0; t < 8; ++t) w2v[t] = W2[t * 16 + lm];
    const float b2s = b2[0];
    const int sel5 = (quad == 0) ? 128 : 0;

    // actual XCD id (performance preference only; sweep below guarantees completion)
    int xcd;
    asm volatile("s_getreg_b32 %0, hwreg(HW_REG_XCC_ID)" : "=s"(xcd));
    xcd &= (NB - 1);

    const int* off = meta + M_OFF;
    int* tc = meta + M_TC;

    for (int bb = 0; bb < NB; ++bb) {
        const int b    = (xcd + bb) & (NB - 1);
        const int base = off[b];
        const int cnt  = off[b + 1] - base;
        if (cnt <= 0) continue;
        const int nt = (cnt + 127) >> 7;

        for (;;) {
            __syncthreads();
            if (tid == 0) sTile = atomicAdd(&tc[b], 1);
            __syncthreads();
            const int t = sTile;
            if (t >= nt) break;

            const int eb   = base + t * 128 + wave * 32;   // this wave's 32 edges
            const int eend = base + cnt;
            int m0 = eb + lm;       if (m0 >= eend) m0 = eend - 1;
            int m1 = eb + 16 + lm;  if (m1 >= eend) m1 = eend - 1;
            const int src0 = sSrc[m0], dst0 = sDst[m0];
            const int src1 = sSrc[m1], dst1 = sDst[m1];

            float dd = 0.f;
            if (lane < 32) {
                const int ps = (lane < 16) ? src0 : src1;
                const int pd = (lane < 16) ? dst0 : dst1;
                const float ax = px[ps * 3 + 0] - py[pd * 3 + 0];
                const float ay = px[ps * 3 + 1] - py[pd * 3 + 1];
                const float az = px[ps * 3 + 2] - py[pd * 3 + 2];
                dd = sqrtf(ax * ax + ay * ay + az * az);
            }
            const float dist0 = __shfl(dd, lm, 64);
            const float dist1 = __shfl(dd, lm + 16, 64);

            short8 fa[4], fb[4];
#pragma unroll
            for (int s = 0; s < 4; ++s) {
                const int kk = s * 32 + quad * 8;
                const short* pa = (s < 2) ? (xb + src0 * NDIM + kk)
                                          : (yb + dst0 * NDIM + (kk - 64));
                const short* pb = (s < 2) ? (xb + src1 * NDIM + kk)
                                          : (yb + dst1 * NDIM + (kk - 64));
                fa[s] = *reinterpret_cast<const short8*>(pa);
                fb[s] = *reinterpret_cast<const short8*>(pb);
            }
            short8 fa4, fb4;
            {
                union { int4v i; short8 s8; } ca, cb;
                const int d0 = (quad == 0) ? pack2(dist0, 1.0f) : 0;
                const int d1 = (quad == 0) ? pack2(dist1, 1.0f) : 0;
                ca.i = int4v{d0, 0, 0, 0};
                cb.i = int4v{d1, 0, 0, 0};
                fa4 = ca.s8; fb4 = cb.s8;
            }

            float p0 = 0.f, p1 = 0.f, p2 = 0.f, p3 = 0.f;
            float q0 = 0.f, q1 = 0.f, q2 = 0.f, q3 = 0.f;
            int zoff = 0;
            asm volatile("" : "+v"(zoff));
            const short* wr  = Wt + zoff + lm * KPAD + quad * 8;
            const short* wr5 = Wt + zoff + lm * KPAD + sel5;

#pragma unroll
            for (int half = 0; half < 2; ++half) {
                if (half) __builtin_amdgcn_sched_barrier(0);
                floatx4 aA[4], aB[4];
#pragma unroll
                for (int u = 0; u < 4; ++u) {
                    aA[u] = floatx4{0.f, 0.f, 0.f, 0.f};
                    aB[u] = floatx4{0.f, 0.f, 0.f, 0.f};
                }
#pragma unroll
                for (int u = 0; u < 4; ++u) {
                    const int t8 = half * 4 + u;
                    const short* bp = wr + t8 * (16 * KPAD);
                    const short8 bg0 = *reinterpret_cast<const short8*>(bp);
                    const short8 bg1 = *reinterpret_cast<const short8*>(bp + 32);
                    const short8 bg2 = *reinterpret_cast<const short8*>(bp + 64);
                    const short8 bg3 = *reinterpret_cast<const short8*>(bp + 96);
                    const short8 bg4 = *reinterpret_cast<const short8*>(wr5 + t8 * (16 * KPAD));
                    aA[u] = __builtin_amdgcn_mfma_f32_16x16x32_bf16(fa[0], bg0, aA[u], 0, 0, 0);
                    aB[u] = __builtin_amdgcn_mfma_f32_16x16x32_bf16(fb[0], bg0, aB[u], 0, 0, 0);
                    aA[u] = __builtin_amdgcn_mfma_f32_16x16x32_bf16(fa[1], bg1, aA[u], 0, 0, 0);
                    aB[u] = __builtin_amdgcn_mfma_f32_16x16x32_bf16(fb[1], bg1, aB[u], 0, 0, 0);
                    aA[u] = __builtin_amdgcn_mfma_f32_16x16x32_bf16(fa[2], bg2, aA[u], 0, 0, 0);
                    aB[u] = __builtin_amdgcn_mfma_f32_16x16x32_bf16(fb[2], bg2, aB[u], 0, 0, 0);
                    aA[u] = __builtin_amdgcn_mfma_f32_16x16x32_bf16(fa[3], bg3, aA[u], 0, 0, 0);
                    aB[u] = __builtin_amdgcn_mfma_f32_16x16x32_bf16(fb[3], bg3, aB[u], 0, 0, 0);
                    aA[u] = __builtin_amdgcn_mfma_f32_16x16x32_bf16(fa4,   bg4, aA[u], 0, 0, 0);
                    aB[u] = __builtin_amdgcn_mfma_f32_16x16x32_bf16(fb4,   bg4, aB[u], 0, 0, 0);
                }
#pragma unroll
                for (int u = 0; u < 4; ++u) {
                    const float w = w2v[half * 4 + u];
                    p0 += fmaxf(aA[u][0], 0.f) * w;
                    p1 += fmaxf(aA[u][1], 0.f) * w;
                    p2 += fmaxf(aA[u][2], 0.f) * w;
                    p3 += fmaxf(aA[u][3], 0.f) * w;
                    q0 += fmaxf(aB[u][0], 0.f) * w;
                    q1 += fmaxf(aB[u][1], 0.f) * w;
                    q2 += fmaxf(aB[u][2], 0.f) * w;
                    q3 += fmaxf(aB[u][3], 0.f) * w;
                }
            }

#pragma unroll
            for (int o = 1; o < 16; o <<= 1) {
                p0 += __shfl_xor(p0, o, 64);
                p1 += __shfl_xor(p1, o, 64);
                p2 += __shfl_xor(p2, o, 64);
                p3 += __shfl_xor(p3, o, 64);
                q0 += __shfl_xor(q0, o, 64);
                q1 += __shfl_xor(q1, o, 64);
                q2 += __shfl_xor(q2, o, 64);
                q3 += __shfl_xor(q3, o, 64);
            }
            if (lm < 4) {
                const float vA = (lm == 0) ? p0 : (lm == 1) ? p1 : (lm == 2) ? p2 : p3;
                const float vB = (lm == 0) ? q0 : (lm == 1) ? q1 : (lm == 2) ? q2 : q3;
                const int rA = t * 128 + wave * 32 + quad * 4 + lm;   // within bucket
                const int rB = rA + 16;
                if (rA < cnt) out[sId[base + rA]] = fmaxf(vA + b2s, 0.f);
                if (rB < cnt) out[sId[base + rB]] = fmaxf(vB + b2s, 0.f);
            }
        }
    }
}

extern "C" void kernel_launch(void* const* d_in, const int* in_sizes, int n_in,
                              void* d_out, int out_size, void* d_ws, size_t ws_size,
                              hipStream_t stream)
{
    const float* x  = (const float*)d_in[0];
    const float* y  = (const float*)d_in[1];
    const int*   ei = (const int*)  d_in[2];
    const float* px = (const float*)d_in[3];
    const float* py = (const float*)d_in[4];
    const float* W1 = (const float*)d_in[5];
    const float* b1 = (const float*)d_in[6];
    const float* W2 = (const float*)d_in[7];
    const float* b2 = (const float*)d_in[8];
    float* out = (float*)d_out;
    const int E = in_sizes[2] / 2;
    const int nnode_elems = in_sizes[0];             // N_NODES * 64
    const int nnode = nnode_elems / NDIM;

    const size_t need_xy   = (size_t)nnode_elems * 2 * sizeof(short);      // 25.6 MB
    const size_t need_sort = need_xy + (size_t)E * 3 * sizeof(int) + 4096; // +12 MB

    if (ws_size >= need_sort) {
        short* xb = (short*)d_ws;
        short* yb = xb + nnode_elems;
        int* sSrc = (int*)(yb + nnode_elems);
        int* sDst = sSrc + E;
        int* sId  = sDst + E;
        int* meta = sId + E;
        const float inv = (float)NB / (float)nnode;

        cvt_kernel<<<dim3(1024), dim3(256), 0, stream>>>(x, y, xb, yb, nnode_elems);
        zero_meta_kernel<<<dim3(1), dim3(64), 0, stream>>>(meta);
        hist_kernel<<<dim3(512), dim3(256), 0, stream>>>(ei, E, inv, meta);
        scan_kernel<<<dim3(1), dim3(64), 0, stream>>>(meta);
        scatter_kernel<<<dim3(512), dim3(256), 0, stream>>>(ei, E, inv, meta,
                                                            sSrc, sDst, sId);
        edge_mlp_sorted_kernel<<<dim3(1024), dim3(256), 0, stream>>>(
            xb, yb, sSrc, sDst, sId, px, py, W1, b1, W2, b2, out, E, meta);
    } else if (ws_size >= need_xy) {
        short* xb = (short*)d_ws;
        short* yb = xb + nnode_elems;
        cvt_kernel<<<dim3(1024), dim3(256), 0, stream>>>(x, y, xb, yb, nnode_elems);
        edge_mlp_kernel<true><<<dim3(1024), dim3(256), 0, stream>>>(
            x, y, xb, yb, ei, px, py, W1, b1, W2, b2, out, E);
    } else {
        edge_mlp_kernel<false><<<dim3(1024), dim3(256), 0, stream>>>(
            x, y, nullptr, nullptr, ei, px, py, W1, b1, W2, b2, out, E);
    }
}

// Round 7
// 222.254 us; speedup vs baseline: 2.4139x; 2.4139x over previous
//
#include <hip/hip_runtime.h>
#include <hip/hip_bf16.h>

// EdgeWeightFromDistance: out[e] = relu(relu([x[src], y[dst], dist] @ W1 + b1) @ W2 + b2)
// E = 1e6, NODE_DIM = 64, HIDDEN = 128.
// R11: R10 split the verdict: FETCH 163->106 MB (byte theory CONFIRMED) but dur 374 µs
//      at 348 GB/s, MfmaUtil 4.3% => the per-tile atomic claim (2 barriers + device
//      atomic on a single cacheline shared by 8 XCDs) serialized everything.
//      Fix: STATIC affinity partition — block bid serves bucket (bid&7) only, tiles
//      t = bid>>3 step gridDim/8. No atomics/barriers in main loop. Coverage is
//      mapping-independent (G16); bid%8==XCD round-robin is a locality-only bet.
//      Buckets are multinomial-balanced (±0.3%) so static split is fair.
//      Compute body identical to R6/R10 -> bit-identical output.

constexpr int NDIM  = 64;
constexpr int HID   = 128;
constexpr int KPAD  = 136;   // bf16 elems per Wt row: 128 data + w1r + b1 + 6 zeros
constexpr int NB    = 8;     // src buckets == XCDs
// meta layout (ints): [0..8) cnt, [8..17) off, [17..25) scatter cur
constexpr int M_CNT = 0, M_OFF = 8, M_CUR = 17, M_TOT = 25;

typedef __attribute__((ext_vector_type(8))) short  short8;
typedef __attribute__((ext_vector_type(4))) int    int4v;
typedef __attribute__((ext_vector_type(4))) float  floatx4;

__device__ __forceinline__ short f2bf(float f) {
    union { __hip_bfloat16 h; short s; } cv;
    cv.h = __float2bfloat16(f);
    return cv.s;
}

__device__ __forceinline__ int pack2(float a, float b) {
    union { __hip_bfloat162 h; int u; } cv;
    cv.h = __float22bfloat162_rn(float2{a, b});
    return cv.u;
}

__device__ __forceinline__ short8 make_afrag_f32(const float* rp) {
    const floatx4 f0 = *reinterpret_cast<const floatx4*>(rp);
    const floatx4 f1 = *reinterpret_cast<const floatx4*>(rp + 4);
    union { int4v i; short8 s8; } cv;
    cv.i.x = pack2(f0.x, f0.y);
    cv.i.y = pack2(f0.z, f0.w);
    cv.i.z = pack2(f1.x, f1.y);
    cv.i.w = pack2(f1.z, f1.w);
    return cv.s8;
}

__device__ __forceinline__ int bucket_of(int s, int nnode) {
    int b = (s * NB) / nnode;          // exact int math; s*8 < 2^31
    return (b > NB - 1) ? NB - 1 : b;
}

// ---- streaming fp32 -> bf16 convert of x and y into workspace ----
__global__ __launch_bounds__(256) void cvt_kernel(
    const float* __restrict__ xin, const float* __restrict__ yin,
    short* __restrict__ xb, short* __restrict__ yb, int nfl)
{
    const int stride = gridDim.x * blockDim.x;
    const int n8 = nfl >> 3;
    for (int i = blockIdx.x * blockDim.x + threadIdx.x; i < n8; i += stride) {
        {
            const floatx4 f0 = *reinterpret_cast<const floatx4*>(xin + i * 8);
            const floatx4 f1 = *reinterpret_cast<const floatx4*>(xin + i * 8 + 4);
            union { int4v v; short8 s; } c;
            c.v.x = pack2(f0.x, f0.y); c.v.y = pack2(f0.z, f0.w);
            c.v.z = pack2(f1.x, f1.y); c.v.w = pack2(f1.z, f1.w);
            *reinterpret_cast<short8*>(xb + i * 8) = c.s;
        }
        {
            const floatx4 f0 = *reinterpret_cast<const floatx4*>(yin + i * 8);
            const floatx4 f1 = *reinterpret_cast<const floatx4*>(yin + i * 8 + 4);
            union { int4v v; short8 s; } c;
            c.v.x = pack2(f0.x, f0.y); c.v.y = pack2(f0.z, f0.w);
            c.v.z = pack2(f1.x, f1.y); c.v.w = pack2(f1.z, f1.w);
            *reinterpret_cast<short8*>(yb + i * 8) = c.s;
        }
    }
}

// ---- bucket partition kernels ----
__global__ __launch_bounds__(64) void zero_meta_kernel(int* __restrict__ meta) {
    if (threadIdx.x < M_TOT) meta[threadIdx.x] = 0;
}

__global__ __launch_bounds__(256) void hist_kernel(
    const int* __restrict__ ei, int E, int nnode, int* __restrict__ meta)
{
    __shared__ int h[NB];
    const int tid = threadIdx.x;
    if (tid < NB) h[tid] = 0;
    __syncthreads();
    const int stride = gridDim.x * blockDim.x;
    for (int e = blockIdx.x * blockDim.x + tid; e < E; e += stride) {
        atomicAdd(&h[bucket_of(ei[e], nnode)], 1);
    }
    __syncthreads();
    if (tid < NB && h[tid] > 0) atomicAdd(&meta[M_CNT + tid], h[tid]);
}

__global__ __launch_bounds__(64) void scan_kernel(int* __restrict__ meta) {
    if (threadIdx.x == 0) {
        int acc = 0;
        for (int b = 0; b < NB; ++b) {
            meta[M_OFF + b] = acc;
            meta[M_CUR + b] = acc;
            acc += meta[M_CNT + b];
        }
        meta[M_OFF + NB] = acc;
    }
}

__global__ __launch_bounds__(256) void scatter_kernel(
    const int* __restrict__ ei, int E, int nnode, int* __restrict__ meta,
    int* __restrict__ sSrc, int* __restrict__ sDst, int* __restrict__ sId)
{
    __shared__ int h[NB], base8[NB], c2[NB];
    const int tid = threadIdx.x;
    const int* srcp = ei;
    const int* dstp = ei + E;
    int* cur = meta + M_CUR;
    const int C  = (E + gridDim.x - 1) / gridDim.x;
    const int lo = blockIdx.x * C;
    const int hi = (lo + C < E) ? (lo + C) : E;
    for (int s0 = lo; s0 < hi; s0 += 256) {
        const int e = s0 + tid;
        const bool valid = e < hi;
        int s = 0, d = 0, b = 0;
        if (tid < NB) { h[tid] = 0; c2[tid] = 0; }
        __syncthreads();
        if (valid) {
            s = srcp[e]; d = dstp[e];
            b = bucket_of(s, nnode);
            atomicAdd(&h[b], 1);
        }
        __syncthreads();
        if (tid < NB && h[tid] > 0) base8[tid] = atomicAdd(&cur[tid], h[tid]);
        __syncthreads();
        if (valid) {
            const int r   = atomicAdd(&c2[b], 1);
            const int pos = base8[b] + r;
            sSrc[pos] = s; sDst[pos] = d; sId[pos] = e;
        }
        __syncthreads();
    }
}

// ================= fallback (R6, verified 62 µs): unsorted edges =================
template <bool BF16GATHER>
__global__ __launch_bounds__(256, 4) void edge_mlp_kernel(
    const float* __restrict__ x, const float* __restrict__ y,
    const short* __restrict__ xb, const short* __restrict__ yb,
    const int*  __restrict__ ei, const float* __restrict__ px,
    const float* __restrict__ py, const float* __restrict__ W1,
    const float* __restrict__ b1, const float* __restrict__ W2,
    const float* __restrict__ b2, float* __restrict__ out, int E)
{
    __shared__ __align__(16) short Wt[HID * KPAD];
    const int tid = threadIdx.x;
    for (int base = 0; base < HID * HID; base += 256 * 8) {
        float f[8];
#pragma unroll
        for (int u = 0; u < 8; ++u) f[u] = W1[base + u * 256 + tid];
#pragma unroll
        for (int u = 0; u < 8; ++u) {
            int i = base + u * 256 + tid;
            Wt[(i & 127) * KPAD + (i >> 7)] = f2bf(f[u]);
        }
    }
    if (tid < HID) {
        const int n = tid;
        Wt[n * KPAD + 128] = f2bf(W1[128 * HID + n]);
        Wt[n * KPAD + 129] = f2bf(b1[n]);
#pragma unroll
        for (int j = 130; j < 136; ++j) Wt[n * KPAD + j] = 0;
    }
    __syncthreads();

    const int lane = tid & 63;
    const int wave = tid >> 6;
    const int quad = lane >> 4;
    const int lm   = lane & 15;

    float w2v[8];
#pragma unroll
    for (int t = 0; t < 8; ++t) w2v[t] = W2[t * 16 + lm];
    const float b2s = b2[0];

    const int* __restrict__ srcp = ei;
    const int* __restrict__ dstp = ei + E;
    const int sel5 = (quad == 0) ? 128 : 0;

    const int ntiles = (E + 127) / 128;
    for (int tile = blockIdx.x; tile < ntiles; tile += gridDim.x) {
        const int mb = tile * 128 + wave * 32;
        int m0 = mb + lm;       if (m0 >= E) m0 = E - 1;
        int m1 = mb + 16 + lm;  if (m1 >= E) m1 = E - 1;
        const int src0 = srcp[m0], dst0 = dstp[m0];
        const int src1 = srcp[m1], dst1 = dstp[m1];

        float dd = 0.f;
        if (lane < 32) {
            const int ps = (lane < 16) ? src0 : src1;
            const int pd = (lane < 16) ? dst0 : dst1;
            const float ax = px[ps * 3 + 0] - py[pd * 3 + 0];
            const float ay = px[ps * 3 + 1] - py[pd * 3 + 1];
            const float az = px[ps * 3 + 2] - py[pd * 3 + 2];
            dd = sqrtf(ax * ax + ay * ay + az * az);
        }
        const float dist0 = __shfl(dd, lm, 64);
        const float dist1 = __shfl(dd, lm + 16, 64);

        short8 fa[4], fb[4];
#pragma unroll
        for (int s = 0; s < 4; ++s) {
            const int kk = s * 32 + quad * 8;
            if (BF16GATHER) {
                const short* pa = (s < 2) ? (xb + src0 * NDIM + kk)
                                          : (yb + dst0 * NDIM + (kk - 64));
                const short* pb = (s < 2) ? (xb + src1 * NDIM + kk)
                                          : (yb + dst1 * NDIM + (kk - 64));
                fa[s] = *reinterpret_cast<const short8*>(pa);
                fb[s] = *reinterpret_cast<const short8*>(pb);
            } else {
                fa[s] = make_afrag_f32((s < 2) ? (x + src0 * NDIM + kk)
                                               : (y + dst0 * NDIM + (kk - 64)));
                fb[s] = make_afrag_f32((s < 2) ? (x + src1 * NDIM + kk)
                                               : (y + dst1 * NDIM + (kk - 64)));
            }
        }
        short8 fa4, fb4;
        {
            union { int4v i; short8 s8; } ca, cb;
            const int d0 = (quad == 0) ? pack2(dist0, 1.0f) : 0;
            const int d1 = (quad == 0) ? pack2(dist1, 1.0f) : 0;
            ca.i = int4v{d0, 0, 0, 0};
            cb.i = int4v{d1, 0, 0, 0};
            fa4 = ca.s8; fb4 = cb.s8;
        }

        float p0 = 0.f, p1 = 0.f, p2 = 0.f, p3 = 0.f;
        float q0 = 0.f, q1 = 0.f, q2 = 0.f, q3 = 0.f;
        int zoff = 0;
        asm volatile("" : "+v"(zoff));
        const short* wr  = Wt + zoff + lm * KPAD + quad * 8;
        const short* wr5 = Wt + zoff + lm * KPAD + sel5;

#pragma unroll
        for (int half = 0; half < 2; ++half) {
            if (half) __builtin_amdgcn_sched_barrier(0);
            floatx4 aA[4], aB[4];
#pragma unroll
            for (int u = 0; u < 4; ++u) {
                aA[u] = floatx4{0.f, 0.f, 0.f, 0.f};
                aB[u] = floatx4{0.f, 0.f, 0.f, 0.f};
            }
#pragma unroll
            for (int u = 0; u < 4; ++u) {
                const int t = half * 4 + u;
                const short* base = wr + t * (16 * KPAD);
                const short8 bg0 = *reinterpret_cast<const short8*>(base);
                const short8 bg1 = *reinterpret_cast<const short8*>(base + 32);
                const short8 bg2 = *reinterpret_cast<const short8*>(base + 64);
                const short8 bg3 = *reinterpret_cast<const short8*>(base + 96);
                const short8 bg4 = *reinterpret_cast<const short8*>(wr5 + t * (16 * KPAD));
                aA[u] = __builtin_amdgcn_mfma_f32_16x16x32_bf16(fa[0], bg0, aA[u], 0, 0, 0);
                aB[u] = __builtin_amdgcn_mfma_f32_16x16x32_bf16(fb[0], bg0, aB[u], 0, 0, 0);
                aA[u] = __builtin_amdgcn_mfma_f32_16x16x32_bf16(fa[1], bg1, aA[u], 0, 0, 0);
                aB[u] = __builtin_amdgcn_mfma_f32_16x16x32_bf16(fb[1], bg1, aB[u], 0, 0, 0);
                aA[u] = __builtin_amdgcn_mfma_f32_16x16x32_bf16(fa[2], bg2, aA[u], 0, 0, 0);
                aB[u] = __builtin_amdgcn_mfma_f32_16x16x32_bf16(fb[2], bg2, aB[u], 0, 0, 0);
                aA[u] = __builtin_amdgcn_mfma_f32_16x16x32_bf16(fa[3], bg3, aA[u], 0, 0, 0);
                aB[u] = __builtin_amdgcn_mfma_f32_16x16x32_bf16(fb[3], bg3, aB[u], 0, 0, 0);
                aA[u] = __builtin_amdgcn_mfma_f32_16x16x32_bf16(fa4,   bg4, aA[u], 0, 0, 0);
                aB[u] = __builtin_amdgcn_mfma_f32_16x16x32_bf16(fb4,   bg4, aB[u], 0, 0, 0);
            }
#pragma unroll
            for (int u = 0; u < 4; ++u) {
                const float w = w2v[half * 4 + u];
                p0 += fmaxf(aA[u][0], 0.f) * w;
                p1 += fmaxf(aA[u][1], 0.f) * w;
                p2 += fmaxf(aA[u][2], 0.f) * w;
                p3 += fmaxf(aA[u][3], 0.f) * w;
                q0 += fmaxf(aB[u][0], 0.f) * w;
                q1 += fmaxf(aB[u][1], 0.f) * w;
                q2 += fmaxf(aB[u][2], 0.f) * w;
                q3 += fmaxf(aB[u][3], 0.f) * w;
            }
        }

#pragma unroll
        for (int off = 1; off < 16; off <<= 1) {
            p0 += __shfl_xor(p0, off, 64);
            p1 += __shfl_xor(p1, off, 64);
            p2 += __shfl_xor(p2, off, 64);
            p3 += __shfl_xor(p3, off, 64);
            q0 += __shfl_xor(q0, off, 64);
            q1 += __shfl_xor(q1, off, 64);
            q2 += __shfl_xor(q2, off, 64);
            q3 += __shfl_xor(q3, off, 64);
        }
        if (lm < 4) {
            const float vA = (lm == 0) ? p0 : (lm == 1) ? p1 : (lm == 2) ? p2 : p3;
            const float vB = (lm == 0) ? q0 : (lm == 1) ? q1 : (lm == 2) ? q2 : q3;
            const int eA = mb + quad * 4 + lm;
            const int eB = mb + 16 + quad * 4 + lm;
            if (eA < E) out[eA] = fmaxf(vA + b2s, 0.f);
            if (eB < E) out[eB] = fmaxf(vB + b2s, 0.f);
        }
    }
}

// ====== sorted main kernel: STATIC XCD-affinity partition (no atomics/barriers) ======
__global__ __launch_bounds__(256, 4) void edge_mlp_sorted_kernel(
    const short* __restrict__ xb, const short* __restrict__ yb,
    const int* __restrict__ sSrc, const int* __restrict__ sDst,
    const int* __restrict__ sId,
    const float* __restrict__ px, const float* __restrict__ py,
    const float* __restrict__ W1, const float* __restrict__ b1,
    const float* __restrict__ W2, const float* __restrict__ b2,
    float* __restrict__ out, int E, const int* __restrict__ meta)
{
    __shared__ __align__(16) short Wt[HID * KPAD];
    const int tid = threadIdx.x;

    for (int base = 0; base < HID * HID; base += 256 * 8) {
        float f[8];
#pragma unroll
        for (int u = 0; u < 8; ++u) f[u] = W1[base + u * 256 + tid];
#pragma unroll
        for (int u = 0; u < 8; ++u) {
            int i = base + u * 256 + tid;
            Wt[(i & 127) * KPAD + (i >> 7)] = f2bf(f[u]);
        }
    }
    if (tid < HID) {
        const int n = tid;
        Wt[n * KPAD + 128] = f2bf(W1[128 * HID + n]);
        Wt[n * KPAD + 129] = f2bf(b1[n]);
#pragma unroll
        for (int j = 130; j < 136; ++j) Wt[n * KPAD + j] = 0;
    }
    __syncthreads();

    const int lane = tid & 63;
    const int wave = tid >> 6;
    const int quad = lane >> 4;
    const int lm   = lane & 15;

    float w2v[8];
#pragma unroll
    for (int t = 0; t < 8; ++t) w2v[t] = W2[t * 16 + lm];
    const float b2s = b2[0];
    const int sel5 = (quad == 0) ? 128 : 0;

    // static affinity: bucket = bid & 7 (== XCD under round-robin dispatch);
    // coverage is exact for ANY mapping — locality is the only thing at stake.
    const int b    = blockIdx.x & (NB - 1);
    const int sub  = blockIdx.x >> 3;
    const int nsub = gridDim.x >> 3;
    const int base = meta[M_OFF + b];
    const int cnt  = meta[M_OFF + b + 1] - base;
    const int nt   = (cnt + 127) >> 7;
    const int eend = base + cnt;

    for (int t = sub; t < nt; t += nsub) {
        const int eb = base + t * 128 + wave * 32;   // this wave's 32 edges
        int m0 = eb + lm;       if (m0 >= eend) m0 = eend - 1;
        int m1 = eb + 16 + lm;  if (m1 >= eend) m1 = eend - 1;
        const int src0 = sSrc[m0], dst0 = sDst[m0];
        const int src1 = sSrc[m1], dst1 = sDst[m1];

        float dd = 0.f;
        if (lane < 32) {
            const int ps = (lane < 16) ? src0 : src1;
            const int pd = (lane < 16) ? dst0 : dst1;
            const float ax = px[ps * 3 + 0] - py[pd * 3 + 0];
            const float ay = px[ps * 3 + 1] - py[pd * 3 + 1];
            const float az = px[ps * 3 + 2] - py[pd * 3 + 2];
            dd = sqrtf(ax * ax + ay * ay + az * az);
        }
        const float dist0 = __shfl(dd, lm, 64);
        const float dist1 = __shfl(dd, lm + 16, 64);

        short8 fa[4], fb[4];
#pragma unroll
        for (int s = 0; s < 4; ++s) {
            const int kk = s * 32 + quad * 8;
            const short* pa = (s < 2) ? (xb + src0 * NDIM + kk)
                                      : (yb + dst0 * NDIM + (kk - 64));
            const short* pb = (s < 2) ? (xb + src1 * NDIM + kk)
                                      : (yb + dst1 * NDIM + (kk - 64));
            fa[s] = *reinterpret_cast<const short8*>(pa);
            fb[s] = *reinterpret_cast<const short8*>(pb);
        }
        short8 fa4, fb4;
        {
            union { int4v i; short8 s8; } ca, cb;
            const int d0 = (quad == 0) ? pack2(dist0, 1.0f) : 0;
            const int d1 = (quad == 0) ? pack2(dist1, 1.0f) : 0;
            ca.i = int4v{d0, 0, 0, 0};
            cb.i = int4v{d1, 0, 0, 0};
            fa4 = ca.s8; fb4 = cb.s8;
        }

        float p0 = 0.f, p1 = 0.f, p2 = 0.f, p3 = 0.f;
        float q0 = 0.f, q1 = 0.f, q2 = 0.f, q3 = 0.f;
        int zoff = 0;
        asm volatile("" : "+v"(zoff));
        const short* wr  = Wt + zoff + lm * KPAD + quad * 8;
        const short* wr5 = Wt + zoff + lm * KPAD + sel5;

#pragma unroll
        for (int half = 0; half < 2; ++half) {
            if (half) __builtin_amdgcn_sched_barrier(0);
            floatx4 aA[4], aB[4];
#pragma unroll
            for (int u = 0; u < 4; ++u) {
                aA[u] = floatx4{0.f, 0.f, 0.f, 0.f};
                aB[u] = floatx4{0.f, 0.f, 0.f, 0.f};
            }
#pragma unroll
            for (int u = 0; u < 4; ++u) {
                const int t8 = half * 4 + u;
                const short* bp = wr + t8 * (16 * KPAD);
                const short8 bg0 = *reinterpret_cast<const short8*>(bp);
                const short8 bg1 = *reinterpret_cast<const short8*>(bp + 32);
                const short8 bg2 = *reinterpret_cast<const short8*>(bp + 64);
                const short8 bg3 = *reinterpret_cast<const short8*>(bp + 96);
                const short8 bg4 = *reinterpret_cast<const short8*>(wr5 + t8 * (16 * KPAD));
                aA[u] = __builtin_amdgcn_mfma_f32_16x16x32_bf16(fa[0], bg0, aA[u], 0, 0, 0);
                aB[u] = __builtin_amdgcn_mfma_f32_16x16x32_bf16(fb[0], bg0, aB[u], 0, 0, 0);
                aA[u] = __builtin_amdgcn_mfma_f32_16x16x32_bf16(fa[1], bg1, aA[u], 0, 0, 0);
                aB[u] = __builtin_amdgcn_mfma_f32_16x16x32_bf16(fb[1], bg1, aB[u], 0, 0, 0);
                aA[u] = __builtin_amdgcn_mfma_f32_16x16x32_bf16(fa[2], bg2, aA[u], 0, 0, 0);
                aB[u] = __builtin_amdgcn_mfma_f32_16x16x32_bf16(fb[2], bg2, aB[u], 0, 0, 0);
                aA[u] = __builtin_amdgcn_mfma_f32_16x16x32_bf16(fa[3], bg3, aA[u], 0, 0, 0);
                aB[u] = __builtin_amdgcn_mfma_f32_16x16x32_bf16(fb[3], bg3, aB[u], 0, 0, 0);
                aA[u] = __builtin_amdgcn_mfma_f32_16x16x32_bf16(fa4,   bg4, aA[u], 0, 0, 0);
                aB[u] = __builtin_amdgcn_mfma_f32_16x16x32_bf16(fb4,   bg4, aB[u], 0, 0, 0);
            }
#pragma unroll
            for (int u = 0; u < 4; ++u) {
                const float w = w2v[half * 4 + u];
                p0 += fmaxf(aA[u][0], 0.f) * w;
                p1 += fmaxf(aA[u][1], 0.f) * w;
                p2 += fmaxf(aA[u][2], 0.f) * w;
                p3 += fmaxf(aA[u][3], 0.f) * w;
                q0 += fmaxf(aB[u][0], 0.f) * w;
                q1 += fmaxf(aB[u][1], 0.f) * w;
                q2 += fmaxf(aB[u][2], 0.f) * w;
                q3 += fmaxf(aB[u][3], 0.f) * w;
            }
        }

#pragma unroll
        for (int o = 1; o < 16; o <<= 1) {
            p0 += __shfl_xor(p0, o, 64);
            p1 += __shfl_xor(p1, o, 64);
            p2 += __shfl_xor(p2, o, 64);
            p3 += __shfl_xor(p3, o, 64);
            q0 += __shfl_xor(q0, o, 64);
            q1 += __shfl_xor(q1, o, 64);
            q2 += __shfl_xor(q2, o, 64);
            q3 += __shfl_xor(q3, o, 64);
        }
        if (lm < 4) {
            const float vA = (lm == 0) ? p0 : (lm == 1) ? p1 : (lm == 2) ? p2 : p3;
            const float vB = (lm == 0) ? q0 : (lm == 1) ? q1 : (lm == 2) ? q2 : q3;
            const int rA = t * 128 + wave * 32 + quad * 4 + lm;   // within bucket
            const int rB = rA + 16;
            if (rA < cnt) out[sId[base + rA]] = fmaxf(vA + b2s, 0.f);
            if (rB < cnt) out[sId[base + rB]] = fmaxf(vB + b2s, 0.f);
        }
    }
}

extern "C" void kernel_launch(void* const* d_in, const int* in_sizes, int n_in,
                              void* d_out, int out_size, void* d_ws, size_t ws_size,
                              hipStream_t stream)
{
    const float* x  = (const float*)d_in[0];
    const float* y  = (const float*)d_in[1];
    const int*   ei = (const int*)  d_in[2];
    const float* px = (const float*)d_in[3];
    const float* py = (const float*)d_in[4];
    const float* W1 = (const float*)d_in[5];
    const float* b1 = (const float*)d_in[6];
    const float* W2 = (const float*)d_in[7];
    const float* b2 = (const float*)d_in[8];
    float* out = (float*)d_out;
    const int E = in_sizes[2] / 2;
    const int nnode_elems = in_sizes[0];             // N_NODES * 64
    const int nnode = nnode_elems / NDIM;

    const size_t need_xy   = (size_t)nnode_elems * 2 * sizeof(short);      // 25.6 MB
    const size_t need_sort = need_xy + (size_t)E * 3 * sizeof(int) + 4096; // +12 MB

    if (ws_size >= need_sort) {
        short* xb = (short*)d_ws;
        short* yb = xb + nnode_elems;
        int* sSrc = (int*)(yb + nnode_elems);
        int* sDst = sSrc + E;
        int* sId  = sDst + E;
        int* meta = sId + E;

        cvt_kernel<<<dim3(1024), dim3(256), 0, stream>>>(x, y, xb, yb, nnode_elems);
        zero_meta_kernel<<<dim3(1), dim3(64), 0, stream>>>(meta);
        hist_kernel<<<dim3(512), dim3(256), 0, stream>>>(ei, E, nnode, meta);
        scan_kernel<<<dim3(1), dim3(64), 0, stream>>>(meta);
        scatter_kernel<<<dim3(512), dim3(256), 0, stream>>>(ei, E, nnode, meta,
                                                            sSrc, sDst, sId);
        edge_mlp_sorted_kernel<<<dim3(1024), dim3(256), 0, stream>>>(
            xb, yb, sSrc, sDst, sId, px, py, W1, b1, W2, b2, out, E, meta);
    } else if (ws_size >= need_xy) {
        short* xb = (short*)d_ws;
        short* yb = xb + nnode_elems;
        cvt_kernel<<<dim3(1024), dim3(256), 0, stream>>>(x, y, xb, yb, nnode_elems);
        edge_mlp_kernel<true><<<dim3(1024), dim3(256), 0, stream>>>(
            x, y, xb, yb, ei, px, py, W1, b1, W2, b2, out, E);
    } else {
        edge_mlp_kernel<false><<<dim3(1024), dim3(256), 0, stream>>>(
            x, y, nullptr, nullptr, ei, px, py, W1, b1, W2, b2, out, E);
    }
}

// Round 9
// 199.402 us; speedup vs baseline: 2.6906x; 1.1146x over previous
//
#include <hip/hip_runtime.h>
#include <hip/hip_bf16.h>

// EdgeWeightFromDistance: out[e] = relu(relu([x[src], y[dst], dist] @ W1 + b1) @ W2 + b2)
// E = 1e6, NODE_DIM = 64, HIDDEN = 128.
// R13: R12 hit the container-failure pattern (R7/R8: lambda; R12: update_dpp builtin —
//      exotic constructs correlate with the infra failure; plain-structure kernels all
//      ran). De-risked: DPP reduce reverted to the R4/R6-proven __shfl_xor butterfly
//      (same lanes/order -> bit-identical). This isolates change (a) of R12:
//      4 edge-sets per wave (64 edges/tile-wave) -> Wt ds_read_b128 traffic halves.
//      LDS-pipe theory: ~70% of runtime = Wt b128 (58.6K cy/CU) + shfl (~25K) +
//      conflicts (~22K); (a) halves the first term. Shfl-per-edge unchanged (1/edge)
//      so SQ_LDS_BANK_CONFLICT should stay ~5.5M — clean isolation.
//      __launch_bounds__(256,2); per-edge math & order unchanged -> absmax 0.00390625.

constexpr int NDIM  = 64;
constexpr int HID   = 128;
constexpr int KPAD  = 136;   // bf16 elems per Wt row: 128 data + w1r + b1 + 6 zeros

typedef __attribute__((ext_vector_type(8))) short  short8;
typedef __attribute__((ext_vector_type(4))) int    int4v;
typedef __attribute__((ext_vector_type(4))) float  floatx4;

__device__ __forceinline__ short f2bf(float f) {
    union { __hip_bfloat16 h; short s; } cv;
    cv.h = __float2bfloat16(f);
    return cv.s;
}

__device__ __forceinline__ int pack2(float a, float b) {
    union { __hip_bfloat162 h; int u; } cv;
    cv.h = __float22bfloat162_rn(float2{a, b});
    return cv.u;
}

__device__ __forceinline__ short8 make_afrag_f32(const float* rp) {
    const floatx4 f0 = *reinterpret_cast<const floatx4*>(rp);
    const floatx4 f1 = *reinterpret_cast<const floatx4*>(rp + 4);
    union { int4v i; short8 s8; } cv;
    cv.i.x = pack2(f0.x, f0.y);
    cv.i.y = pack2(f0.z, f0.w);
    cv.i.z = pack2(f1.x, f1.y);
    cv.i.w = pack2(f1.z, f1.w);
    return cv.s8;
}

// ---- streaming fp32 -> bf16 convert of x and y into workspace ----
__global__ __launch_bounds__(256) void cvt_kernel(
    const float* __restrict__ xin, const float* __restrict__ yin,
    short* __restrict__ xb, short* __restrict__ yb, int nfl)
{
    const int stride = gridDim.x * blockDim.x;
    const int n8 = nfl >> 3;
    for (int i = blockIdx.x * blockDim.x + threadIdx.x; i < n8; i += stride) {
        {
            const floatx4 f0 = *reinterpret_cast<const floatx4*>(xin + i * 8);
            const floatx4 f1 = *reinterpret_cast<const floatx4*>(xin + i * 8 + 4);
            union { int4v v; short8 s; } c;
            c.v.x = pack2(f0.x, f0.y); c.v.y = pack2(f0.z, f0.w);
            c.v.z = pack2(f1.x, f1.y); c.v.w = pack2(f1.z, f1.w);
            *reinterpret_cast<short8*>(xb + i * 8) = c.s;
        }
        {
            const floatx4 f0 = *reinterpret_cast<const floatx4*>(yin + i * 8);
            const floatx4 f1 = *reinterpret_cast<const floatx4*>(yin + i * 8 + 4);
            union { int4v v; short8 s; } c;
            c.v.x = pack2(f0.x, f0.y); c.v.y = pack2(f0.z, f0.w);
            c.v.z = pack2(f1.x, f1.y); c.v.w = pack2(f1.z, f1.w);
            *reinterpret_cast<short8*>(yb + i * 8) = c.s;
        }
    }
}

template <bool BF16GATHER>
__global__ __launch_bounds__(256, 2) void edge_mlp_kernel(
    const float* __restrict__ x, const float* __restrict__ y,
    const short* __restrict__ xb, const short* __restrict__ yb,
    const int*  __restrict__ ei, const float* __restrict__ px,
    const float* __restrict__ py, const float* __restrict__ W1,
    const float* __restrict__ b1, const float* __restrict__ W2,
    const float* __restrict__ b2, float* __restrict__ out, int E)
{
    __shared__ __align__(16) short Wt[HID * KPAD];   // W1^T [n][k] bf16 (+ fold rows)
    const int tid = threadIdx.x;

    // ---- stage W1[0:128][0:128] transposed into LDS ----
    for (int base = 0; base < HID * HID; base += 256 * 8) {
        float f[8];
#pragma unroll
        for (int u = 0; u < 8; ++u) f[u] = W1[base + u * 256 + tid];
#pragma unroll
        for (int u = 0; u < 8; ++u) {
            int i = base + u * 256 + tid;
            Wt[(i & 127) * KPAD + (i >> 7)] = f2bf(f[u]);
        }
    }
    if (tid < HID) {
        const int n = tid;
        Wt[n * KPAD + 128] = f2bf(W1[128 * HID + n]);
        Wt[n * KPAD + 129] = f2bf(b1[n]);
#pragma unroll
        for (int j = 130; j < 136; ++j) Wt[n * KPAD + j] = 0;
    }
    __syncthreads();

    const int lane = tid & 63;
    const int wave = tid >> 6;
    const int quad = lane >> 4;
    const int lm   = lane & 15;   // A-frag row m; B-frag/C-D col n (within tile)

    float w2v[8];
#pragma unroll
    for (int t = 0; t < 8; ++t) w2v[t] = W2[t * 16 + lm];
    const float b2s = b2[0];

    const int* __restrict__ srcp = ei;
    const int* __restrict__ dstp = ei + E;
    const int sel5 = (quad == 0) ? 128 : 0;   // fold-step k-offset

    const int ntiles = (E + 255) / 256;       // 256 edges per block-iter, 64 per wave
    for (int tile = blockIdx.x; tile < ntiles; tile += gridDim.x) {
        const int mb = tile * 256 + wave * 64;

        // ---- indices for 4 sets of 16 edges (clamped) ----
        int S[4], D[4];
#pragma unroll
        for (int s = 0; s < 4; ++s) {
            int m = mb + s * 16 + lm;
            if (m >= E) m = E - 1;
            S[s] = srcp[m]; D[s] = dstp[m];
        }

        // ---- dist: each lane computes its own edge (mb + lane) ----
        const int sq = (quad == 0) ? S[0] : (quad == 1) ? S[1] : (quad == 2) ? S[2] : S[3];
        const int dq = (quad == 0) ? D[0] : (quad == 1) ? D[1] : (quad == 2) ? D[2] : D[3];
        float dd;
        {
            const float ax = px[sq * 3 + 0] - py[dq * 3 + 0];
            const float ay = px[sq * 3 + 1] - py[dq * 3 + 1];
            const float az = px[sq * 3 + 2] - py[dq * 3 + 2];
            dd = sqrtf(ax * ax + ay * ay + az * az);
        }
        float di[4];
#pragma unroll
        for (int s = 0; s < 4; ++s) di[s] = __shfl(dd, s * 16 + lm, 64);

        // ---- A fragments: 4 sets x 4 k-chunks ----
        short8 fr[4][4];
#pragma unroll
        for (int s = 0; s < 4; ++s) {
#pragma unroll
            for (int c = 0; c < 4; ++c) {
                const int kk = c * 32 + quad * 8;
                if (BF16GATHER) {
                    const short* p = (c < 2) ? (xb + S[s] * NDIM + kk)
                                             : (yb + D[s] * NDIM + (kk - 64));
                    fr[s][c] = *reinterpret_cast<const short8*>(p);
                } else {
                    fr[s][c] = make_afrag_f32((c < 2) ? (x + S[s] * NDIM + kk)
                                                      : (y + D[s] * NDIM + (kk - 64)));
                }
            }
        }
        // fold A-frags: k=128 -> dist, k=129 -> 1.0 (quad 0 only)
        short8 f4[4];
#pragma unroll
        for (int s = 0; s < 4; ++s) {
            union { int4v i; short8 s8; } cc;
            cc.i = int4v{(quad == 0) ? pack2(di[s], 1.0f) : 0, 0, 0, 0};
            f4[s] = cc.s8;
        }

        float pv[4][4];
#pragma unroll
        for (int s = 0; s < 4; ++s)
#pragma unroll
            for (int r = 0; r < 4; ++r) pv[s][r] = 0.f;

        // zoff guard defeats LICM of Wt values (keeps Wt streaming from LDS)
        int zoff = 0;
        asm volatile("" : "+v"(zoff));
        const short* wr  = Wt + zoff + lm * KPAD + quad * 8;
        const short* wr5 = Wt + zoff + lm * KPAD + sel5;

        // ---- two halves of 4 n-tiles; 4 sets share each Wt read ----
#pragma unroll
        for (int half = 0; half < 2; ++half) {
            if (half) __builtin_amdgcn_sched_barrier(0);
            floatx4 ac[4][4];
#pragma unroll
            for (int s = 0; s < 4; ++s)
#pragma unroll
                for (int u = 0; u < 4; ++u) ac[s][u] = floatx4{0.f, 0.f, 0.f, 0.f};

#pragma unroll
            for (int u = 0; u < 4; ++u) {
                const int t = half * 4 + u;
                const short* bp = wr + t * (16 * KPAD);
                const short8 bg0 = *reinterpret_cast<const short8*>(bp);
                const short8 bg1 = *reinterpret_cast<const short8*>(bp + 32);
                const short8 bg2 = *reinterpret_cast<const short8*>(bp + 64);
                const short8 bg3 = *reinterpret_cast<const short8*>(bp + 96);
                const short8 bg4 = *reinterpret_cast<const short8*>(wr5 + t * (16 * KPAD));
#pragma unroll
                for (int s = 0; s < 4; ++s) {
                    ac[s][u] = __builtin_amdgcn_mfma_f32_16x16x32_bf16(fr[s][0], bg0, ac[s][u], 0, 0, 0);
                    ac[s][u] = __builtin_amdgcn_mfma_f32_16x16x32_bf16(fr[s][1], bg1, ac[s][u], 0, 0, 0);
                    ac[s][u] = __builtin_amdgcn_mfma_f32_16x16x32_bf16(fr[s][2], bg2, ac[s][u], 0, 0, 0);
                    ac[s][u] = __builtin_amdgcn_mfma_f32_16x16x32_bf16(fr[s][3], bg3, ac[s][u], 0, 0, 0);
                    ac[s][u] = __builtin_amdgcn_mfma_f32_16x16x32_bf16(f4[s],    bg4, ac[s][u], 0, 0, 0);
                }
            }
            // epilogue slice: relu + dot-W2 (t order preserved per edge)
#pragma unroll
            for (int u = 0; u < 4; ++u) {
                const float w = w2v[half * 4 + u];
#pragma unroll
                for (int s = 0; s < 4; ++s) {
                    pv[s][0] += fmaxf(ac[s][u][0], 0.f) * w;
                    pv[s][1] += fmaxf(ac[s][u][1], 0.f) * w;
                    pv[s][2] += fmaxf(ac[s][u][2], 0.f) * w;
                    pv[s][3] += fmaxf(ac[s][u][3], 0.f) * w;
                }
            }
        }

        // ---- 16-lane reduce via __shfl_xor butterfly (R4/R6-proven, bit-identical) ----
#pragma unroll
        for (int off = 1; off < 16; off <<= 1) {
#pragma unroll
            for (int s = 0; s < 4; ++s) {
                pv[s][0] += __shfl_xor(pv[s][0], off, 64);
                pv[s][1] += __shfl_xor(pv[s][1], off, 64);
                pv[s][2] += __shfl_xor(pv[s][2], off, 64);
                pv[s][3] += __shfl_xor(pv[s][3], off, 64);
            }
        }

        if (lm < 4) {
#pragma unroll
            for (int s = 0; s < 4; ++s) {
                const float v = (lm == 0) ? pv[s][0] : (lm == 1) ? pv[s][1]
                              : (lm == 2) ? pv[s][2] : pv[s][3];
                const int e = mb + s * 16 + quad * 4 + lm;
                if (e < E) out[e] = fmaxf(v + b2s, 0.f);
            }
        }
    }
}

extern "C" void kernel_launch(void* const* d_in, const int* in_sizes, int n_in,
                              void* d_out, int out_size, void* d_ws, size_t ws_size,
                              hipStream_t stream)
{
    const float* x  = (const float*)d_in[0];
    const float* y  = (const float*)d_in[1];
    const int*   ei = (const int*)  d_in[2];
    const float* px = (const float*)d_in[3];
    const float* py = (const float*)d_in[4];
    const float* W1 = (const float*)d_in[5];
    const float* b1 = (const float*)d_in[6];
    const float* W2 = (const float*)d_in[7];
    const float* b2 = (const float*)d_in[8];
    float* out = (float*)d_out;
    const int E = in_sizes[2] / 2;
    const int nnode_elems = in_sizes[0];             // N_NODES * 64

    const size_t need = (size_t)nnode_elems * 2 * sizeof(short);
    if (ws_size >= need) {
        short* xb = (short*)d_ws;
        short* yb = xb + nnode_elems;
        cvt_kernel<<<dim3(1024), dim3(256), 0, stream>>>(x, y, xb, yb, nnode_elems);
        edge_mlp_kernel<true><<<dim3(1024), dim3(256), 0, stream>>>(
            x, y, xb, yb, ei, px, py, W1, b1, W2, b2, out, E);
    } else {
        edge_mlp_kernel<false><<<dim3(1024), dim3(256), 0, stream>>>(
            x, y, nullptr, nullptr, ei, px, py, W1, b1, W2, b2, out, E);
    }
}

// Round 10
// 166.274 us; speedup vs baseline: 3.2266x; 1.1992x over previous
//
#include <hip/hip_runtime.h>
#include <hip/hip_bf16.h>

// EdgeWeightFromDistance: out[e] = relu(relu([x[src], y[dst], dist] @ W1 + b1) @ W2 + b2)
// E = 1e6, NODE_DIM = 64, HIDDEN = 128.
// R14: R13 spilled (WRITE 138 MB, 4-set = 64 VGPR frags + 64 AGPR acc) — reverted to
//      R6's 2-set core. Clean test of the Wt-read theory, registers counted (~222):
//      (a) Wt for t=0..5 hoisted to registers wg[6][4] (96 VGPR, loaded once,
//          statically indexed after full unroll); only t=6,7 streamed from LDS.
//          In-loop ds_read_b128: 40 -> 8 per wave-tile (-80%).
//      (b) fold-MFMA deleted: acc init = b1, dist*w1r applied as VALU FMA in the
//          per-half epilogue (MFMA 80 -> 64/tile). bf16 products exact in fp32 ->
//          only an fp32 add-order change (absmax may shift ~1e-6).
//      launch_bounds (256,2); no lambda / no DPP (prior infra-failure triggers).
//      Clean-experiment gates: WRITE ~4 MB, VGPR 220-235. If dur stays ~62 µs with
//      gates passed -> LDS theory refuted -> gather path is the floor by elimination.

constexpr int NDIM  = 64;
constexpr int HID   = 128;
constexpr int KPAD  = 136;   // bf16 elems per Wt row (chunks 0..15 used; pad keeps layout)

typedef __attribute__((ext_vector_type(8))) short  short8;
typedef __attribute__((ext_vector_type(4))) int    int4v;
typedef __attribute__((ext_vector_type(4))) float  floatx4;

__device__ __forceinline__ short f2bf(float f) {
    union { __hip_bfloat16 h; short s; } cv;
    cv.h = __float2bfloat16(f);
    return cv.s;
}

__device__ __forceinline__ int pack2(float a, float b) {
    union { __hip_bfloat162 h; int u; } cv;
    cv.h = __float22bfloat162_rn(float2{a, b});
    return cv.u;
}

__device__ __forceinline__ short8 make_afrag_f32(const float* rp) {
    const floatx4 f0 = *reinterpret_cast<const floatx4*>(rp);
    const floatx4 f1 = *reinterpret_cast<const floatx4*>(rp + 4);
    union { int4v i; short8 s8; } cv;
    cv.i.x = pack2(f0.x, f0.y);
    cv.i.y = pack2(f0.z, f0.w);
    cv.i.z = pack2(f1.x, f1.y);
    cv.i.w = pack2(f1.z, f1.w);
    return cv.s8;
}

__device__ __forceinline__ float bf2f(short s) {
    union { __hip_bfloat16 h; short v; } cv;
    cv.v = s;
    return __bfloat162float(cv.h);
}

// ---- streaming fp32 -> bf16 convert of x and y into workspace ----
__global__ __launch_bounds__(256) void cvt_kernel(
    const float* __restrict__ xin, const float* __restrict__ yin,
    short* __restrict__ xb, short* __restrict__ yb, int nfl)
{
    const int stride = gridDim.x * blockDim.x;
    const int n8 = nfl >> 3;
    for (int i = blockIdx.x * blockDim.x + threadIdx.x; i < n8; i += stride) {
        {
            const floatx4 f0 = *reinterpret_cast<const floatx4*>(xin + i * 8);
            const floatx4 f1 = *reinterpret_cast<const floatx4*>(xin + i * 8 + 4);
            union { int4v v; short8 s; } c;
            c.v.x = pack2(f0.x, f0.y); c.v.y = pack2(f0.z, f0.w);
            c.v.z = pack2(f1.x, f1.y); c.v.w = pack2(f1.z, f1.w);
            *reinterpret_cast<short8*>(xb + i * 8) = c.s;
        }
        {
            const floatx4 f0 = *reinterpret_cast<const floatx4*>(yin + i * 8);
            const floatx4 f1 = *reinterpret_cast<const floatx4*>(yin + i * 8 + 4);
            union { int4v v; short8 s; } c;
            c.v.x = pack2(f0.x, f0.y); c.v.y = pack2(f0.z, f0.w);
            c.v.z = pack2(f1.x, f1.y); c.v.w = pack2(f1.z, f1.w);
            *reinterpret_cast<short8*>(yb + i * 8) = c.s;
        }
    }
}

template <bool BF16GATHER>
__global__ __launch_bounds__(256, 2) void edge_mlp_kernel(
    const float* __restrict__ x, const float* __restrict__ y,
    const short* __restrict__ xb, const short* __restrict__ yb,
    const int*  __restrict__ ei, const float* __restrict__ px,
    const float* __restrict__ py, const float* __restrict__ W1,
    const float* __restrict__ b1, const float* __restrict__ W2,
    const float* __restrict__ b2, float* __restrict__ out, int E)
{
    __shared__ __align__(16) short Wt[HID * KPAD];   // W1^T [n][k] bf16 (chunks 0..15)
    const int tid = threadIdx.x;

    // ---- stage W1[0:128][0:128] transposed into LDS (no fold rows needed) ----
    for (int base = 0; base < HID * HID; base += 256 * 8) {
        float f[8];
#pragma unroll
        for (int u = 0; u < 8; ++u) f[u] = W1[base + u * 256 + tid];
#pragma unroll
        for (int u = 0; u < 8; ++u) {
            int i = base + u * 256 + tid;
            Wt[(i & 127) * KPAD + (i >> 7)] = f2bf(f[u]);
        }
    }
    __syncthreads();

    const int lane = tid & 63;
    const int wave = tid >> 6;
    const int quad = lane >> 4;
    const int lm   = lane & 15;   // A-frag row m; B-frag/C-D col n (within tile)

    // per-lane column constants: n = t*16 + lm
    float w2v[8], w1rv[8], b1v[8];
#pragma unroll
    for (int t = 0; t < 8; ++t) {
        const int n = t * 16 + lm;
        w2v[t]  = W2[n];
        w1rv[t] = bf2f(f2bf(W1[128 * HID + n]));   // bf16-rounded, as MFMA saw it
        b1v[t]  = bf2f(f2bf(b1[n]));
    }
    const float b2s = b2[0];

    const int* __restrict__ srcp = ei;
    const int* __restrict__ dstp = ei + E;

    // ---- hoist Wt t=0..5 into registers (static indexing after unroll) ----
    const short* wr = Wt + lm * KPAD + quad * 8;
    short8 wg[6][4];
#pragma unroll
    for (int t = 0; t < 6; ++t)
#pragma unroll
        for (int c = 0; c < 4; ++c)
            wg[t][c] = *reinterpret_cast<const short8*>(wr + t * (16 * KPAD) + c * 32);

    const int ntiles = (E + 127) / 128;       // 128 edges per block-iter, 32 per wave
    for (int tile = blockIdx.x; tile < ntiles; tile += gridDim.x) {
        const int mb = tile * 128 + wave * 32;
        int m0 = mb + lm;       if (m0 >= E) m0 = E - 1;
        int m1 = mb + 16 + lm;  if (m1 >= E) m1 = E - 1;
        const int src0 = srcp[m0], dst0 = dstp[m0];
        const int src1 = srcp[m1], dst1 = dstp[m1];

        // ---- dist: lanes 0..31 own edge mb+lane ----
        float dd = 0.f;
        if (lane < 32) {
            const int ps = (lane < 16) ? src0 : src1;
            const int pd = (lane < 16) ? dst0 : dst1;
            const float ax = px[ps * 3 + 0] - py[pd * 3 + 0];
            const float ay = px[ps * 3 + 1] - py[pd * 3 + 1];
            const float az = px[ps * 3 + 2] - py[pd * 3 + 2];
            dd = sqrtf(ax * ax + ay * ay + az * az);
        }
        // per-lane fold dists: rows m = quad*4 + r (set A), 16 + quad*4 + r (set B)
        float dfA[4], dfB[4];
#pragma unroll
        for (int r = 0; r < 4; ++r) {
            const float dA = __shfl(dd, quad * 4 + r, 64);
            const float dB = __shfl(dd, 16 + quad * 4 + r, 64);
            dfA[r] = bf2f(f2bf(dA));   // bf16-rounded, as the fold-MFMA saw it
            dfB[r] = bf2f(f2bf(dB));
        }

        // ---- A fragments: row m, k = c*32 + quad*8 + j ----
        short8 fa[4], fb[4];
#pragma unroll
        for (int c = 0; c < 4; ++c) {
            const int kk = c * 32 + quad * 8;
            if (BF16GATHER) {
                const short* pa = (c < 2) ? (xb + src0 * NDIM + kk)
                                          : (yb + dst0 * NDIM + (kk - 64));
                const short* pb = (c < 2) ? (xb + src1 * NDIM + kk)
                                          : (yb + dst1 * NDIM + (kk - 64));
                fa[c] = *reinterpret_cast<const short8*>(pa);
                fb[c] = *reinterpret_cast<const short8*>(pb);
            } else {
                fa[c] = make_afrag_f32((c < 2) ? (x + src0 * NDIM + kk)
                                               : (y + dst0 * NDIM + (kk - 64)));
                fb[c] = make_afrag_f32((c < 2) ? (x + src1 * NDIM + kk)
                                               : (y + dst1 * NDIM + (kk - 64)));
            }
        }

        float p0 = 0.f, p1 = 0.f, p2 = 0.f, p3 = 0.f;
        float q0 = 0.f, q1 = 0.f, q2 = 0.f, q3 = 0.f;

        // zoff guard only for the streamed t=6,7 reads
        int zoff = 0;
        asm volatile("" : "+v"(zoff));
        const short* wrs = Wt + zoff + lm * KPAD + quad * 8;

#pragma unroll
        for (int half = 0; half < 2; ++half) {
            if (half) __builtin_amdgcn_sched_barrier(0);

            floatx4 aA[4], aB[4];
#pragma unroll
            for (int u = 0; u < 4; ++u) {
                const int t = half * 4 + u;
                const float bi = b1v[t];
                aA[u] = floatx4{bi, bi, bi, bi};   // b1 in accumulator init
                aB[u] = floatx4{bi, bi, bi, bi};
            }
#pragma unroll
            for (int u = 0; u < 4; ++u) {
                const int t = half * 4 + u;
                short8 bg0, bg1, bg2, bg3;
                if (t < 6) {
                    bg0 = wg[t][0]; bg1 = wg[t][1]; bg2 = wg[t][2]; bg3 = wg[t][3];
                } else {
                    const short* bp = wrs + t * (16 * KPAD);
                    bg0 = *reinterpret_cast<const short8*>(bp);
                    bg1 = *reinterpret_cast<const short8*>(bp + 32);
                    bg2 = *reinterpret_cast<const short8*>(bp + 64);
                    bg3 = *reinterpret_cast<const short8*>(bp + 96);
                }
                aA[u] = __builtin_amdgcn_mfma_f32_16x16x32_bf16(fa[0], bg0, aA[u], 0, 0, 0);
                aB[u] = __builtin_amdgcn_mfma_f32_16x16x32_bf16(fb[0], bg0, aB[u], 0, 0, 0);
                aA[u] = __builtin_amdgcn_mfma_f32_16x16x32_bf16(fa[1], bg1, aA[u], 0, 0, 0);
                aB[u] = __builtin_amdgcn_mfma_f32_16x16x32_bf16(fb[1], bg1, aB[u], 0, 0, 0);
                aA[u] = __builtin_amdgcn_mfma_f32_16x16x32_bf16(fa[2], bg2, aA[u], 0, 0, 0);
                aB[u] = __builtin_amdgcn_mfma_f32_16x16x32_bf16(fb[2], bg2, aB[u], 0, 0, 0);
                aA[u] = __builtin_amdgcn_mfma_f32_16x16x32_bf16(fa[3], bg3, aA[u], 0, 0, 0);
                aB[u] = __builtin_amdgcn_mfma_f32_16x16x32_bf16(fb[3], bg3, aB[u], 0, 0, 0);
            }
            // per-half epilogue: + dist*w1r (VALU fold), relu, dot-W2
#pragma unroll
            for (int u = 0; u < 4; ++u) {
                const int t = half * 4 + u;
                const float w  = w2v[t];
                const float wr1 = w1rv[t];
                p0 += fmaxf(fmaf(dfA[0], wr1, aA[u][0]), 0.f) * w;
                p1 += fmaxf(fmaf(dfA[1], wr1, aA[u][1]), 0.f) * w;
                p2 += fmaxf(fmaf(dfA[2], wr1, aA[u][2]), 0.f) * w;
                p3 += fmaxf(fmaf(dfA[3], wr1, aA[u][3]), 0.f) * w;
                q0 += fmaxf(fmaf(dfB[0], wr1, aB[u][0]), 0.f) * w;
                q1 += fmaxf(fmaf(dfB[1], wr1, aB[u][1]), 0.f) * w;
                q2 += fmaxf(fmaf(dfB[2], wr1, aB[u][2]), 0.f) * w;
                q3 += fmaxf(fmaf(dfB[3], wr1, aB[u][3]), 0.f) * w;
            }
        }

        // ---- 16-lane reduce via __shfl_xor butterfly (R4/R6-proven) ----
#pragma unroll
        for (int off = 1; off < 16; off <<= 1) {
            p0 += __shfl_xor(p0, off, 64);
            p1 += __shfl_xor(p1, off, 64);
            p2 += __shfl_xor(p2, off, 64);
            p3 += __shfl_xor(p3, off, 64);
            q0 += __shfl_xor(q0, off, 64);
            q1 += __shfl_xor(q1, off, 64);
            q2 += __shfl_xor(q2, off, 64);
            q3 += __shfl_xor(q3, off, 64);
        }
        if (lm < 4) {
            const float vA = (lm == 0) ? p0 : (lm == 1) ? p1 : (lm == 2) ? p2 : p3;
            const float vB = (lm == 0) ? q0 : (lm == 1) ? q1 : (lm == 2) ? q2 : q3;
            const int eA = mb + quad * 4 + lm;
            const int eB = mb + 16 + quad * 4 + lm;
            if (eA < E) out[eA] = fmaxf(vA + b2s, 0.f);
            if (eB < E) out[eB] = fmaxf(vB + b2s, 0.f);
        }
    }
}

extern "C" void kernel_launch(void* const* d_in, const int* in_sizes, int n_in,
                              void* d_out, int out_size, void* d_ws, size_t ws_size,
                              hipStream_t stream)
{
    const float* x  = (const float*)d_in[0];
    const float* y  = (const float*)d_in[1];
    const int*   ei = (const int*)  d_in[2];
    const float* px = (const float*)d_in[3];
    const float* py = (const float*)d_in[4];
    const float* W1 = (const float*)d_in[5];
    const float* b1 = (const float*)d_in[6];
    const float* W2 = (const float*)d_in[7];
    const float* b2 = (const float*)d_in[8];
    float* out = (float*)d_out;
    const int E = in_sizes[2] / 2;
    const int nnode_elems = in_sizes[0];             // N_NODES * 64

    const size_t need = (size_t)nnode_elems * 2 * sizeof(short);
    if (ws_size >= need) {
        short* xb = (short*)d_ws;
        short* yb = xb + nnode_elems;
        cvt_kernel<<<dim3(1024), dim3(256), 0, stream>>>(x, y, xb, yb, nnode_elems);
        edge_mlp_kernel<true><<<dim3(1024), dim3(256), 0, stream>>>(
            x, y, xb, yb, ei, px, py, W1, b1, W2, b2, out, E);
    } else {
        edge_mlp_kernel<false><<<dim3(1024), dim3(256), 0, stream>>>(
            x, y, nullptr, nullptr, ei, px, py, W1, b1, W2, b2, out, E);
    }
}